// Round 6
// baseline (24454.620 us; speedup 1.0000x reference)
//
#include <hip/hip_runtime.h>

// DeepLSTM: B=32, S=512, IN=512, H=1024, 3H=3072, L=4
// out (fp32): cur [32][512][1024] | h_finals [4][32][1024] | c_finals [4][32][1024]
// ws (~192 MiB): Xp fp32 | hbuf (packed hi|lo words, TRANSPOSED [k][batch]) | bar
// Precision: split-bf16 (hi+lo) 3-term MFMA everywhere (~2^-16 rel); Xp fp32;
// inter-layer y fp32 staged in d_out's cur region; h packed (hi,lo) bf16 words;
// c in fp32 registers.
// R1: distributed-flag barrier replaced 512-way same-line fetch_add.
// R2: master/broadcast barrier killed the poll storm (polls weren't dominant).
// R3: all mid-kernel coherence on agent-scope (sc1) relaxed atomics; no full-L2
//     wbl2/inv in the loop. 23.5 -> 15.9 us/step, variance gone.
// R4: kc stagger + deeper unroll eased LLC request serialization. -> 10.7 us/step.
// R5: transposed hbuf[k][b] coalesced reads/stores. -> 8.6 us/step. Only 1.24x from
//     8x fewer line-requests => now BYTE-bound on the sc1/LLC path (~3.7 TB/s eff).
// R6: HALVE the h-read volume structurally. 256 blocks = 128 slices (8 units ->
//     24 W rows, W LDS ~100KB) x 2 batch-groups (16 batches). One 64-thr wave per
//     block reads h for its 16 batches only (64KB/step) and computes TWO 12-row
//     MFMA groups per kc (6 MFMA/kc, 2 acc sets). Total sc1 reads 32 -> 16 MB/step;
//     total MFMA work unchanged; elementwise does 2 units (2 cell states)/thread.

typedef unsigned short ushort_t;
typedef __attribute__((ext_vector_type(4))) float f32x4;
typedef __attribute__((ext_vector_type(8))) short s16x8;
typedef __attribute__((ext_vector_type(4))) short s16x4;

__device__ __forceinline__ unsigned short f2bf(float f) {
  union { float f; unsigned u; } v; v.f = f;
  unsigned r = (v.u + 0x7fffu + ((v.u >> 16) & 1u)) >> 16;
  return (unsigned short)r;
}
__device__ __forceinline__ float bf2f(unsigned short h) {
  union { unsigned u; float f; } v; v.u = ((unsigned)h) << 16; return v.f;
}
__device__ __forceinline__ void split2(float x, short& hi, short& lo) {
  unsigned short h = f2bf(x);
  hi = (short)h;
  lo = (short)f2bf(x - bf2f(h));
}

// ---------------- split-bf16 GEMM: C[m][n] = sum_k A[m][k]*Bw[n][k] + bias[n] ----------------
// A: fp32 [M][K]; Bw: fp32 [N][K]; C: fp32 [M][N]. BM=BN=128, BK=32. (unchanged)
#define BM 128
#define BN 128
#define BK 32
__global__ __launch_bounds__(256) void k_gemm_split(
    const float* __restrict__ A, const float* __restrict__ Bw,
    const float* __restrict__ bias, float* __restrict__ C,
    int M, int N, int K) {
  __shared__ short Ah[BM * BK], Al[BM * BK];
  __shared__ short Bh[BN * BK], Bl[BN * BK];
  const int tid = threadIdx.x;
  const int nbm = M / BM;
  const int bm = blockIdx.x % nbm;
  const int bn = blockIdx.x / nbm;
  const int lane = tid & 63;
  const int wave = tid >> 6;
  const int wm = (wave & 1) * 64;
  const int wn = (wave >> 1) * 64;
  const int q = lane >> 4;
  f32x4 acc[4][4] = {};
  const int nk = K / BK;
  for (int kt = 0; kt < nk; ++kt) {
    __syncthreads();
    const int kb = kt * BK;
#pragma unroll
    for (int i = 0; i < 4; ++i) {
      int idx = tid + i * 256;            // 0..1023
      int row = idx >> 3, c4 = (idx & 7) * 4;
      f32x4 ta = *(const f32x4*)(A + (size_t)(bm * BM + row) * K + kb + c4);
      s16x4 h4, l4;
#pragma unroll
      for (int j = 0; j < 4; ++j) { short hh, ll; split2(ta[j], hh, ll); h4[j] = hh; l4[j] = ll; }
      *(s16x4*)&Ah[row * BK + c4] = h4;
      *(s16x4*)&Al[row * BK + c4] = l4;
      f32x4 tb = *(const f32x4*)(Bw + (size_t)(bn * BN + row) * K + kb + c4);
#pragma unroll
      for (int j = 0; j < 4; ++j) { short hh, ll; split2(tb[j], hh, ll); h4[j] = hh; l4[j] = ll; }
      *(s16x4*)&Bh[row * BK + c4] = h4;
      *(s16x4*)&Bl[row * BK + c4] = l4;
    }
    __syncthreads();
    s16x8 ah[4], al[4], bh[4], bl[4];
#pragma unroll
    for (int i = 0; i < 4; ++i) {
      int r = (wm + i * 16 + (lane & 15)) * BK + q * 8;
      ah[i] = *(const s16x8*)&Ah[r];
      al[i] = *(const s16x8*)&Al[r];
      int rb = (wn + i * 16 + (lane & 15)) * BK + q * 8;
      bh[i] = *(const s16x8*)&Bh[rb];
      bl[i] = *(const s16x8*)&Bl[rb];
    }
#pragma unroll
    for (int mi = 0; mi < 4; ++mi)
#pragma unroll
      for (int ni = 0; ni < 4; ++ni) {
        acc[mi][ni] = __builtin_amdgcn_mfma_f32_16x16x32_bf16(ah[mi], bh[ni], acc[mi][ni], 0, 0, 0);
        acc[mi][ni] = __builtin_amdgcn_mfma_f32_16x16x32_bf16(al[mi], bh[ni], acc[mi][ni], 0, 0, 0);
        acc[mi][ni] = __builtin_amdgcn_mfma_f32_16x16x32_bf16(ah[mi], bl[ni], acc[mi][ni], 0, 0, 0);
      }
  }
#pragma unroll
  for (int mi = 0; mi < 4; ++mi)
#pragma unroll
    for (int ni = 0; ni < 4; ++ni) {
      int col = bn * BN + wn + ni * 16 + (lane & 15);
      float bv = bias[col];
#pragma unroll
      for (int r = 0; r < 4; ++r) {
        int row = bm * BM + wm + mi * 16 + q * 4 + r;
        C[(size_t)row * N + col] = acc[mi][ni][r] + bv;
      }
    }
}

// ---------------- persistent recurrent kernel (one layer, 512 steps) ----------------
// 256 blocks x 64 threads (1 wave). bid -> (slice 0..127, grp 0..1):
//   slice = ((bid&7)<<4) | ((bid>>3)&15)  (adjacent slices share an XCD), grp = bid>>7.
// Block owns 8 units u0=slice*8 (24 W rows) for 16 batches b0=grp*16.
// LDS: W_hh 24 rows (+pad to 25 n-slots) hi+lo = 100KB; red [16][28] f32.
// hbuf: uint [2][1024 k][32 b], word = (bf16_hi<<16)|bf16_lo, all sc1 atomics.
// bar (per layer, 512 ints): [0..255] per-block step flags, [256] epoch word.
__global__ __launch_bounds__(64) void k_recurrent(
    const float* __restrict__ Xp,     // [16384][3072] fp32: x@Wih^T + b (rows m=b*512+t)
    const float* __restrict__ Whh,    // [3072][1024] fp32 (original weights)
    unsigned* __restrict__ hbuf,      // [2][1024][32] packed h words (pre-zeroed)
    float* __restrict__ yOut,         // [32][512][1024] fp32: layer output (cur region)
    float* __restrict__ hOut,         // [32][1024] f32
    float* __restrict__ cOut,         // [32][1024] f32
    int* __restrict__ bar)            // [512] ints: flags[256] + epoch, zeroed
{
  __shared__ short Wh[128 * 25 * 8];  // [kq][25 n-slots][8] hi, 50 KB (24 rows + pad)
  __shared__ short Wl[128 * 25 * 8];  // lo, 50 KB
  __shared__ float red[16][28];       // [batch][col]; col = r*12 + gate*4 + ui (24 used)
  const int tid = threadIdx.x;        // 0..63 (single wave)
  const int bid = blockIdx.x;
  const int slice = ((bid & 7) << 4) | ((bid >> 3) & 15);  // bijective on [0,128)
  const int grp = bid >> 7;
  const int u0 = slice * 8;
  const int b0 = grp * 16;

  // stage + split W_hh: 24 rows; n = r*12 + G*4 + ui -> row = G*1024 + u0 + r*4 + ui
  for (int p = tid; p < 3072; p += 64) {
    int n = p >> 7, kq = p & 127;
    int r = (n > 11) ? 1 : 0, rr = n - r * 12, G = rr >> 2, ui = rr & 3;
    int row = G * 1024 + u0 + r * 4 + ui;
    const float* src = Whh + (size_t)row * 1024 + kq * 8;
    f32x4 v0 = *(const f32x4*)src;
    f32x4 v1 = *(const f32x4*)(src + 4);
    s16x4 h4, l4;
#pragma unroll
    for (int j = 0; j < 4; ++j) { short hh, ll; split2(v0[j], hh, ll); h4[j] = hh; l4[j] = ll; }
    *(s16x4*)&Wh[(kq * 25 + n) * 8] = h4;
    *(s16x4*)&Wl[(kq * 25 + n) * 8] = l4;
#pragma unroll
    for (int j = 0; j < 4; ++j) { short hh, ll; split2(v1[j], hh, ll); h4[j] = hh; l4[j] = ll; }
    *(s16x4*)&Wh[(kq * 25 + n) * 8 + 4] = h4;
    *(s16x4*)&Wl[(kq * 25 + n) * 8 + 4] = l4;
  }

  const int m = tid & 15;             // batch-in-group (A row) / elementwise batch
  const int q = tid >> 4;             // k quad / elementwise unit-pair index
  const bool nvalid = m < 12;
  const int kc0 = slice & 31;         // per-block kc stagger (anti-hot-line)
  float cA = 0.f, cB = 0.f;           // cell states for units u0+q and u0+q+4
  __syncthreads();

  for (int t = 0; t < 512; ++t) {
    const int par = t & 1;
    // --- gate-input loads hoisted above matvec (latency hides under MFMA loop) ---
    const size_t mrow = (size_t)(b0 + m) * 512 + t;
    const float xiA = Xp[mrow * 3072 + (u0 + q)];
    const float xiB = Xp[mrow * 3072 + (u0 + q + 4)];
    const float xgA = Xp[mrow * 3072 + 1024 + (u0 + q)];
    const float xgB = Xp[mrow * 3072 + 1024 + (u0 + q + 4)];
    const float xoA = Xp[mrow * 3072 + 2048 + (u0 + q)];
    const float xoB = Xp[mrow * 3072 + 2048 + (u0 + q + 4)];

    // --- matvec: D[batch][n] = sum_k h[batch][k] * W[n][k], split-bf16 3-term,
    //     TWO 12-row groups per kc (r=0: units u0..u0+3, r=1: u0+4..u0+7) ---
    const unsigned* hp = hbuf + (size_t)par * 32768 + (b0 + m);
    f32x4 acc[2][3] = {};
#pragma unroll 8
    for (int kci = 0; kci < 32; ++kci) {
      const int kc = (kci + kc0) & 31;
      const unsigned* p = hp + (kc * 32 + q * 8) * 32;  // + j*32 per word
      unsigned w0 = __hip_atomic_load(p + 0 * 32, __ATOMIC_RELAXED, __HIP_MEMORY_SCOPE_AGENT);
      unsigned w1 = __hip_atomic_load(p + 1 * 32, __ATOMIC_RELAXED, __HIP_MEMORY_SCOPE_AGENT);
      unsigned w2 = __hip_atomic_load(p + 2 * 32, __ATOMIC_RELAXED, __HIP_MEMORY_SCOPE_AGENT);
      unsigned w3 = __hip_atomic_load(p + 3 * 32, __ATOMIC_RELAXED, __HIP_MEMORY_SCOPE_AGENT);
      unsigned w4 = __hip_atomic_load(p + 4 * 32, __ATOMIC_RELAXED, __HIP_MEMORY_SCOPE_AGENT);
      unsigned w5 = __hip_atomic_load(p + 5 * 32, __ATOMIC_RELAXED, __HIP_MEMORY_SCOPE_AGENT);
      unsigned w6 = __hip_atomic_load(p + 6 * 32, __ATOMIC_RELAXED, __HIP_MEMORY_SCOPE_AGENT);
      unsigned w7 = __hip_atomic_load(p + 7 * 32, __ATOMIC_RELAXED, __HIP_MEMORY_SCOPE_AGENT);
      union { unsigned u[4]; s16x8 v; } H, L;
      H.u[0] = (w0 >> 16) | (w1 & 0xffff0000u); L.u[0] = (w0 & 0xffffu) | (w1 << 16);
      H.u[1] = (w2 >> 16) | (w3 & 0xffff0000u); L.u[1] = (w2 & 0xffffu) | (w3 << 16);
      H.u[2] = (w4 >> 16) | (w5 & 0xffff0000u); L.u[2] = (w4 & 0xffffu) | (w5 << 16);
      H.u[3] = (w6 >> 16) | (w7 & 0xffff0000u); L.u[3] = (w6 & 0xffffu) | (w7 << 16);
      s16x8 ahf = H.v, alf = L.v;
#pragma unroll
      for (int r = 0; r < 2; ++r) {
        s16x8 bhf = {}, blf = {};
        if (nvalid) {
          bhf = *(const s16x8*)&Wh[(((kc * 4 + q) * 25) + r * 12 + m) * 8];
          blf = *(const s16x8*)&Wl[(((kc * 4 + q) * 25) + r * 12 + m) * 8];
        }
        acc[r][0] = __builtin_amdgcn_mfma_f32_16x16x32_bf16(ahf, bhf, acc[r][0], 0, 0, 0);
        acc[r][1] = __builtin_amdgcn_mfma_f32_16x16x32_bf16(alf, bhf, acc[r][1], 0, 0, 0);
        acc[r][2] = __builtin_amdgcn_mfma_f32_16x16x32_bf16(ahf, blf, acc[r][2], 0, 0, 0);
      }
    }
    // D layout: lane (m,q) reg j holds D[batch=q*4+j][n = r*12 + m]
#pragma unroll
    for (int r = 0; r < 2; ++r)
#pragma unroll
      for (int j = 0; j < 4; ++j)
        red[q * 4 + j][r * 12 + m] = acc[r][0][j] + acc[r][1][j] + acc[r][2][j];
    __syncthreads();

    // --- elementwise cell update: thread (m=batch, q=unit) does units q and q+4 ---
    {
      float igA = xiA + red[m][q];
      float ggA = xgA + red[m][4 + q];
      float ogA = xoA + red[m][8 + q];
      float igB = xiB + red[m][12 + q];
      float ggB = xgB + red[m][16 + q];
      float ogB = xoB + red[m][20 + q];
      float siA = 1.f / (1.f + expf(-igA));
      cA += siA * tanhf(ggA);
      float hA = (1.f / (1.f + expf(-ogA))) * tanhf(cA);
      float siB = 1.f / (1.f + expf(-igB));
      cB += siB * tanhf(ggB);
      float hB = (1.f / (1.f + expf(-ogB))) * tanhf(cB);
      short hh, hl;
      split2(hA, hh, hl);
      unsigned wA = ((unsigned)(unsigned short)hh << 16) | (unsigned)(unsigned short)hl;
      split2(hB, hh, hl);
      unsigned wB = ((unsigned)(unsigned short)hh << 16) | (unsigned)(unsigned short)hl;
      // transposed store [unit][batch]: 16 lanes of a quad share a 64B line
      size_t hwA = (size_t)(1 - par) * 32768 + (size_t)(u0 + q) * 32 + (b0 + m);
      size_t hwB = (size_t)(1 - par) * 32768 + (size_t)(u0 + q + 4) * 32 + (b0 + m);
      __hip_atomic_store(&hbuf[hwA], wA, __ATOMIC_RELAXED, __HIP_MEMORY_SCOPE_AGENT);
      __hip_atomic_store(&hbuf[hwB], wB, __ATOMIC_RELAXED, __HIP_MEMORY_SCOPE_AGENT);
      yOut[mrow * 1024 + (u0 + q)] = hA;
      yOut[mrow * 1024 + (u0 + q + 4)] = hB;
      if (t == 511) {
        hOut[(size_t)(b0 + m) * 1024 + (u0 + q)] = hA;
        hOut[(size_t)(b0 + m) * 1024 + (u0 + q + 4)] = hB;
        cOut[(size_t)(b0 + m) * 1024 + (u0 + q)] = cA;
        cOut[(size_t)(b0 + m) * 1024 + (u0 + q + 4)] = cB;
      }
    }
    if (t == 511) break;  // no successor step: kernel-end flush publishes outputs

    // ---- two-level grid barrier, zero cache-maintenance (as R3-R5) ----
    const int tgt = t + 1;
    asm volatile("s_waitcnt vmcnt(0)" ::: "memory");
    __syncthreads();
    if (bid == 0) {
      if (tid == 0)
        __hip_atomic_store(&bar[0], tgt, __ATOMIC_RELAXED, __HIP_MEMORY_SCOPE_AGENT);
      for (;;) {
        int f0 = __hip_atomic_load(&bar[tid], __ATOMIC_RELAXED, __HIP_MEMORY_SCOPE_AGENT);
        int f1 = __hip_atomic_load(&bar[tid + 64], __ATOMIC_RELAXED, __HIP_MEMORY_SCOPE_AGENT);
        int f2 = __hip_atomic_load(&bar[tid + 128], __ATOMIC_RELAXED, __HIP_MEMORY_SCOPE_AGENT);
        int f3 = __hip_atomic_load(&bar[tid + 192], __ATOMIC_RELAXED, __HIP_MEMORY_SCOPE_AGENT);
        if (__syncthreads_and((f0 >= tgt) && (f1 >= tgt) && (f2 >= tgt) && (f3 >= tgt))) break;
        __builtin_amdgcn_s_sleep(1);
      }
      if (tid == 0)
        __hip_atomic_store(&bar[256], tgt, __ATOMIC_RELAXED, __HIP_MEMORY_SCOPE_AGENT);
    } else {
      if (tid == 0) {
        __hip_atomic_store(&bar[bid], tgt, __ATOMIC_RELAXED, __HIP_MEMORY_SCOPE_AGENT);
        while (__hip_atomic_load(&bar[256], __ATOMIC_RELAXED, __HIP_MEMORY_SCOPE_AGENT) < tgt)
          __builtin_amdgcn_s_sleep(1);
      }
      __syncthreads();
    }
    asm volatile("" ::: "memory");  // no hoisting h loads above poll
  }
}

// ---------------- host ----------------
extern "C" void kernel_launch(void* const* d_in, const int* in_sizes, int n_in,
                              void* d_out, int out_size, void* d_ws, size_t ws_size,
                              hipStream_t stream) {
  const float* x     = (const float*)d_in[0];
  const float* w_ih0 = (const float*)d_in[1];
  const float* w_hh0 = (const float*)d_in[2];
  const float* b0v   = (const float*)d_in[3];
  const float* w_ihr = (const float*)d_in[4];
  const float* w_hhr = (const float*)d_in[5];
  const float* b_r   = (const float*)d_in[6];
  float* out = (float*)d_out;

  char* ws = (char*)d_ws;
  float*    Xp   = (float*)(ws);                   // 201,326,592 B
  unsigned* hbuf = (unsigned*)(ws + 201326592);    //     262,144 B (packed h words)
  int*      bar  = (int*)(ws + 201588736);         //       8,192 B (~192.3 MiB total)

  float* yBuf     = out;                 // cur region doubles as inter-layer y staging
  float* hOutBase = out + 16777216;
  float* cOutBase = out + 16777216 + 131072;

  hipMemsetAsync(bar, 0, 8192, stream);

  for (int l = 0; l < 4; ++l) {
    const float* wih  = (l == 0) ? w_ih0 : (w_ihr + (size_t)(l - 1) * 3072 * 1024);
    const float* whh  = (l == 0) ? w_hh0 : (w_hhr + (size_t)(l - 1) * 3072 * 1024);
    const float* bias = (l == 0) ? b0v : (b_r + (size_t)(l - 1) * 3072);
    const int K = (l == 0) ? 512 : 1024;
    const float* Ain = (l == 0) ? x : yBuf;
    dim3 ggrid((16384 / BM) * (3072 / BN));
    k_gemm_split<<<ggrid, 256, 0, stream>>>(Ain, wih, bias, Xp, 16384, 3072, K);
    hipMemsetAsync(hbuf, 0, 262144, stream);
    float* hO = hOutBase + (size_t)l * 32768;
    float* cO = cOutBase + (size_t)l * 32768;
    int* barL = bar + l * 512;   // flags[256] + epoch[1] per layer; fresh zeroed region
    void* args[] = { (void*)&Xp, (void*)&whh, (void*)&hbuf, (void*)&yBuf,
                     (void*)&hO, (void*)&cO, (void*)&barL };
    if (hipLaunchCooperativeKernel((void*)k_recurrent, dim3(256), dim3(64),
                                   args, 0, stream) != hipSuccess) {
      // fallback: plain launch (256 blocks, ~104KB LDS, 64 thr -> all co-resident)
      k_recurrent<<<dim3(256), dim3(64), 0, stream>>>(Xp, whh, hbuf, yBuf,
                                                      hO, cO, barL);
    }
  }
}

// Round 7
// 19469.896 us; speedup vs baseline: 1.2560x; 1.2560x over previous
//
#include <hip/hip_runtime.h>

// DeepLSTM: B=32, S=512, IN=512, H=1024, 3H=3072, L=4
// out (fp32): cur [32][512][1024] | h_finals [4][32][1024] | c_finals [4][32][1024]
// ws (~192 MiB): Xp fp32 | hbuf (packed hi|lo words, [k/8][batch][8]) | bar
// Precision: split-bf16 (hi+lo) 3-term MFMA everywhere (~2^-16 rel); Xp fp32;
// inter-layer y fp32 staged in d_out's cur region; h packed (hi,lo) bf16 words;
// c in fp32 register.
// R1: distributed-flag barrier replaced 512-way same-line fetch_add.
// R2: master/broadcast barrier killed the poll storm (polls weren't dominant).
// R3: sc1 relaxed atomics for h + barrier; no full-L2 wbl2/inv. -> 15.9 us/step.
// R4: kc stagger + deeper unroll. -> 10.7 us/step (request serialization).
// R5: transposed hbuf coalesced lines. -> 8.6 us/step.
// R6: FAILED (halved bytes, halved waves -> 11.1 us/step). Falsified "byte-bound";
//     read is LATENCY x QUEUE-DEPTH bound (Little's law: 2 waves x 48 x 64B/375ns
//     = 4.2 TB/s ~= observed 3.7 TB/s; R6's 1 wave -> 2.1 TB/s, matches regression).
// R7: revert to R5 shape; raise bytes-in-flight 8x per instruction instead.
//     hbuf relayout [k/8][b][8]: lane's 8 words per kc contiguous -> 4 x u64 sc1
//     atomic loads per kc (was 8 x u32). 63-instr vmcnt window now holds 32KB/wave
//     -> demand >> LLC ceiling -> read collapses to LLC BW floor (~2.5 us/step).
//     Also: W LDS pitch 12->13 n-slots (kills the 6-way bank conflict, stride 208B
//     -> ~2-way = free) and red pad 16->17.

typedef unsigned short ushort_t;
typedef __attribute__((ext_vector_type(4))) float f32x4;
typedef __attribute__((ext_vector_type(8))) short s16x8;
typedef __attribute__((ext_vector_type(4))) short s16x4;

__device__ __forceinline__ unsigned short f2bf(float f) {
  union { float f; unsigned u; } v; v.f = f;
  unsigned r = (v.u + 0x7fffu + ((v.u >> 16) & 1u)) >> 16;
  return (unsigned short)r;
}
__device__ __forceinline__ float bf2f(unsigned short h) {
  union { unsigned u; float f; } v; v.u = ((unsigned)h) << 16; return v.f;
}
__device__ __forceinline__ void split2(float x, short& hi, short& lo) {
  unsigned short h = f2bf(x);
  hi = (short)h;
  lo = (short)f2bf(x - bf2f(h));
}

// unpack 8 packed h-words (hi<<16|lo) from four u64 into hi/lo bf16 fragments
__device__ __forceinline__ void unpack8(unsigned long long d0, unsigned long long d1,
                                        unsigned long long d2, unsigned long long d3,
                                        s16x8& hi, s16x8& lo) {
  unsigned w0 = (unsigned)d0, w1 = (unsigned)(d0 >> 32);
  unsigned w2 = (unsigned)d1, w3 = (unsigned)(d1 >> 32);
  unsigned w4 = (unsigned)d2, w5 = (unsigned)(d2 >> 32);
  unsigned w6 = (unsigned)d3, w7 = (unsigned)(d3 >> 32);
  union { unsigned u[4]; s16x8 v; } H, L;
  H.u[0] = (w0 >> 16) | (w1 & 0xffff0000u); L.u[0] = (w0 & 0xffffu) | (w1 << 16);
  H.u[1] = (w2 >> 16) | (w3 & 0xffff0000u); L.u[1] = (w2 & 0xffffu) | (w3 << 16);
  H.u[2] = (w4 >> 16) | (w5 & 0xffff0000u); L.u[2] = (w4 & 0xffffu) | (w5 << 16);
  H.u[3] = (w6 >> 16) | (w7 & 0xffff0000u); L.u[3] = (w6 & 0xffffu) | (w7 << 16);
  hi = H.v; lo = L.v;
}

// ---------------- split-bf16 GEMM: C[m][n] = sum_k A[m][k]*Bw[n][k] + bias[n] ----------------
// A: fp32 [M][K]; Bw: fp32 [N][K]; C: fp32 [M][N]. BM=BN=128, BK=32. (unchanged)
#define BM 128
#define BN 128
#define BK 32
__global__ __launch_bounds__(256) void k_gemm_split(
    const float* __restrict__ A, const float* __restrict__ Bw,
    const float* __restrict__ bias, float* __restrict__ C,
    int M, int N, int K) {
  __shared__ short Ah[BM * BK], Al[BM * BK];
  __shared__ short Bh[BN * BK], Bl[BN * BK];
  const int tid = threadIdx.x;
  const int nbm = M / BM;
  const int bm = blockIdx.x % nbm;
  const int bn = blockIdx.x / nbm;
  const int lane = tid & 63;
  const int wave = tid >> 6;
  const int wm = (wave & 1) * 64;
  const int wn = (wave >> 1) * 64;
  const int q = lane >> 4;
  f32x4 acc[4][4] = {};
  const int nk = K / BK;
  for (int kt = 0; kt < nk; ++kt) {
    __syncthreads();
    const int kb = kt * BK;
#pragma unroll
    for (int i = 0; i < 4; ++i) {
      int idx = tid + i * 256;            // 0..1023
      int row = idx >> 3, c4 = (idx & 7) * 4;
      f32x4 ta = *(const f32x4*)(A + (size_t)(bm * BM + row) * K + kb + c4);
      s16x4 h4, l4;
#pragma unroll
      for (int j = 0; j < 4; ++j) { short hh, ll; split2(ta[j], hh, ll); h4[j] = hh; l4[j] = ll; }
      *(s16x4*)&Ah[row * BK + c4] = h4;
      *(s16x4*)&Al[row * BK + c4] = l4;
      f32x4 tb = *(const f32x4*)(Bw + (size_t)(bn * BN + row) * K + kb + c4);
#pragma unroll
      for (int j = 0; j < 4; ++j) { short hh, ll; split2(tb[j], hh, ll); h4[j] = hh; l4[j] = ll; }
      *(s16x4*)&Bh[row * BK + c4] = h4;
      *(s16x4*)&Bl[row * BK + c4] = l4;
    }
    __syncthreads();
    s16x8 ah[4], al[4], bh[4], bl[4];
#pragma unroll
    for (int i = 0; i < 4; ++i) {
      int r = (wm + i * 16 + (lane & 15)) * BK + q * 8;
      ah[i] = *(const s16x8*)&Ah[r];
      al[i] = *(const s16x8*)&Al[r];
      int rb = (wn + i * 16 + (lane & 15)) * BK + q * 8;
      bh[i] = *(const s16x8*)&Bh[rb];
      bl[i] = *(const s16x8*)&Bl[rb];
    }
#pragma unroll
    for (int mi = 0; mi < 4; ++mi)
#pragma unroll
      for (int ni = 0; ni < 4; ++ni) {
        acc[mi][ni] = __builtin_amdgcn_mfma_f32_16x16x32_bf16(ah[mi], bh[ni], acc[mi][ni], 0, 0, 0);
        acc[mi][ni] = __builtin_amdgcn_mfma_f32_16x16x32_bf16(al[mi], bh[ni], acc[mi][ni], 0, 0, 0);
        acc[mi][ni] = __builtin_amdgcn_mfma_f32_16x16x32_bf16(ah[mi], bl[ni], acc[mi][ni], 0, 0, 0);
      }
  }
#pragma unroll
  for (int mi = 0; mi < 4; ++mi)
#pragma unroll
    for (int ni = 0; ni < 4; ++ni) {
      int col = bn * BN + wn + ni * 16 + (lane & 15);
      float bv = bias[col];
#pragma unroll
      for (int r = 0; r < 4; ++r) {
        int row = bm * BM + wm + mi * 16 + q * 4 + r;
        C[(size_t)row * N + col] = acc[mi][ni][r] + bv;
      }
    }
}

// ---------------- persistent recurrent kernel (one layer, 512 steps) ----------------
// 256 blocks x 128 threads (2 waves). Wave g in {0,1}: batch group g*16..g*16+15.
// Block owns 4 hidden units u0..u0+3 (all 3 gates): s = (bid&7)*32 + (bid>>3) so
// consecutive unit-slices land on the same XCD.
// LDS: split W_hh tile, 12 rows x K=1024 at 13-slot pitch, hi+lo = 52KB + red ~2KB.
// hbuf: uint [2][128 kblk][32 b][8 j], word = (bf16_hi<<16)|bf16_lo (k = kblk*8+j).
// A lane's 8 words per kc are CONTIGUOUS -> 4 x u64 sc1 atomic loads per kc.
// bar (per layer, 512 ints): [0..255] per-block step flags, [256] epoch word.
__global__ __launch_bounds__(128) void k_recurrent(
    const float* __restrict__ Xp,     // [16384][3072] fp32: x@Wih^T + b (rows m=b*512+t)
    const float* __restrict__ Whh,    // [3072][1024] fp32 (original weights)
    unsigned* __restrict__ hbuf,      // [2][32768] packed h words (pre-zeroed)
    float* __restrict__ yOut,         // [32][512][1024] fp32: layer output (cur region)
    float* __restrict__ hOut,         // [32][1024] f32
    float* __restrict__ cOut,         // [32][1024] f32
    int* __restrict__ bar)            // [512] ints: flags[256] + epoch, zeroed
{
  __shared__ short Wh[128 * 13 * 8];  // [kq][13 n-slots][8] hi, 26 KB (12 rows + pad)
  __shared__ short Wl[128 * 13 * 8];  // lo, 26 KB
  __shared__ float red[2][16][17];    // [g][batch][col(padded)], col: 0-3 i, 4-7 g, 8-11 o
  const int tid = threadIdx.x;
  const int lane = tid & 63;
  const int g = tid >> 6;             // wave = batch group
  const int bid = blockIdx.x;
  const int s = ((bid & 7) << 5) | (bid >> 3);  // XCD-grouped unit slice, bijective on [0,256)
  const int u0 = s * 4;
  const int b0 = g * 16;

  // stage + split W_hh rows for this slice (one-time, both waves cooperate)
  for (int p = tid; p < 1536; p += 128) {
    int n = p >> 7, kq = p & 127;
    int row = (n < 4) ? (u0 + n) : (n < 8) ? (1024 + u0 + (n - 4)) : (2048 + u0 + (n - 8));
    const float* src = Whh + (size_t)row * 1024 + kq * 8;
    f32x4 v0 = *(const f32x4*)src;
    f32x4 v1 = *(const f32x4*)(src + 4);
    s16x4 h4, l4;
#pragma unroll
    for (int j = 0; j < 4; ++j) { short hh, ll; split2(v0[j], hh, ll); h4[j] = hh; l4[j] = ll; }
    *(s16x4*)&Wh[(kq * 13 + n) * 8] = h4;
    *(s16x4*)&Wl[(kq * 13 + n) * 8] = l4;
#pragma unroll
    for (int j = 0; j < 4; ++j) { short hh, ll; split2(v1[j], hh, ll); h4[j] = hh; l4[j] = ll; }
    *(s16x4*)&Wh[(kq * 13 + n) * 8 + 4] = h4;
    *(s16x4*)&Wl[(kq * 13 + n) * 8 + 4] = l4;
  }

  const int m = lane & 15;            // batch-in-group (A row)
  const int q = lane >> 4;            // k quad
  const bool nvalid = m < 12;
  const int eb = (tid >> 2) & 15;     // elementwise batch-in-group
  const int eu = tid & 3;             // elementwise unit
  const int kc0 = s & 31;             // per-block kc stagger (anti-hot-line)
  float c = 0.f;                      // cell state in register across all 512 steps
  __syncthreads();

  for (int t = 0; t < 512; ++t) {
    const int par = t & 1;
    // --- gate-input loads hoisted above matvec: latency hides under MFMA loop ---
    const size_t mrow = (size_t)(b0 + eb) * 512 + t;
    const float xi = Xp[mrow * 3072 + (u0 + eu)];
    const float xg = Xp[mrow * 3072 + 1024 + (u0 + eu)];
    const float xo = Xp[mrow * 3072 + 2048 + (u0 + eu)];

    // --- matvec: D[batch][n] = sum_k h[batch][k] * W[n][k], split-bf16 3-term ---
    // hbuf word idx = kblk*256 + b*8 + j (kblk = kc*4+q). Lane (m,q) reads its 8
    // words as 4 contiguous u64 sc1 atomic loads -> 512B/instr per wave in flight.
    const unsigned long long* hp64 =
        (const unsigned long long*)hbuf + (size_t)par * 16384 + (size_t)(b0 + m) * 4;
    f32x4 a0 = {0.f, 0.f, 0.f, 0.f}, a1 = a0, a2 = a0;
#pragma unroll 16
    for (int kci = 0; kci < 32; ++kci) {
      const int kc = (kci + kc0) & 31;
      const unsigned long long* p = hp64 + (size_t)(kc * 4 + q) * 128;
      unsigned long long d0 = __hip_atomic_load(p + 0, __ATOMIC_RELAXED, __HIP_MEMORY_SCOPE_AGENT);
      unsigned long long d1 = __hip_atomic_load(p + 1, __ATOMIC_RELAXED, __HIP_MEMORY_SCOPE_AGENT);
      unsigned long long d2 = __hip_atomic_load(p + 2, __ATOMIC_RELAXED, __HIP_MEMORY_SCOPE_AGENT);
      unsigned long long d3 = __hip_atomic_load(p + 3, __ATOMIC_RELAXED, __HIP_MEMORY_SCOPE_AGENT);
      s16x8 ahf, alf;
      unpack8(d0, d1, d2, d3, ahf, alf);
      s16x8 bhf = {}, blf = {};
      if (nvalid) {
        bhf = *(const s16x8*)&Wh[(((kc * 4 + q) * 13) + m) * 8];
        blf = *(const s16x8*)&Wl[(((kc * 4 + q) * 13) + m) * 8];
      }
      a0 = __builtin_amdgcn_mfma_f32_16x16x32_bf16(ahf, bhf, a0, 0, 0, 0);
      a1 = __builtin_amdgcn_mfma_f32_16x16x32_bf16(alf, bhf, a1, 0, 0, 0);
      a2 = __builtin_amdgcn_mfma_f32_16x16x32_bf16(ahf, blf, a2, 0, 0, 0);
    }
#pragma unroll
    for (int r = 0; r < 4; ++r)
      red[g][q * 4 + r][m] = a0[r] + a1[r] + a2[r];
    __syncthreads();

    // --- elementwise cell update: one thread per (g,b,u) ---
    {
      float ig = xi + red[g][eb][eu];
      float gg = xg + red[g][eb][4 + eu];
      float og = xo + red[g][eb][8 + eu];
      float si = 1.f / (1.f + expf(-ig));
      float tg = tanhf(gg);
      c += si * tg;
      float so = 1.f / (1.f + expf(-og));
      float h = so * tanhf(c);
      short hh, hl;
      split2(h, hh, hl);
      unsigned hword = ((unsigned)(unsigned short)hh << 16) | (unsigned)(unsigned short)hl;
      const int ku = u0 + eu;
      size_t hw = (size_t)(1 - par) * 32768 + (size_t)(ku >> 3) * 256
                + (size_t)(b0 + eb) * 8 + (ku & 7);
      __hip_atomic_store(&hbuf[hw], hword, __ATOMIC_RELAXED, __HIP_MEMORY_SCOPE_AGENT);
      yOut[mrow * 1024 + ku] = h;
      if (t == 511) {
        hOut[(size_t)(b0 + eb) * 1024 + ku] = h;
        cOut[(size_t)(b0 + eb) * 1024 + ku] = c;
      }
    }
    if (t == 511) break;  // no successor step: kernel-end flush publishes outputs

    // ---- two-level grid barrier, zero cache-maintenance (as R3-R5) ----
    const int tgt = t + 1;
    asm volatile("s_waitcnt vmcnt(0)" ::: "memory");
    __syncthreads();
    if (bid == 0) {
      if (tid == 0)
        __hip_atomic_store(&bar[0], tgt, __ATOMIC_RELAXED, __HIP_MEMORY_SCOPE_AGENT);
      for (;;) {
        int f0 = __hip_atomic_load(&bar[tid], __ATOMIC_RELAXED, __HIP_MEMORY_SCOPE_AGENT);
        int f1 = __hip_atomic_load(&bar[tid + 128], __ATOMIC_RELAXED, __HIP_MEMORY_SCOPE_AGENT);
        if (__syncthreads_and((f0 >= tgt) && (f1 >= tgt))) break;
        __builtin_amdgcn_s_sleep(1);
      }
      if (tid == 0)
        __hip_atomic_store(&bar[256], tgt, __ATOMIC_RELAXED, __HIP_MEMORY_SCOPE_AGENT);
    } else {
      if (tid == 0) {
        __hip_atomic_store(&bar[bid], tgt, __ATOMIC_RELAXED, __HIP_MEMORY_SCOPE_AGENT);
        while (__hip_atomic_load(&bar[256], __ATOMIC_RELAXED, __HIP_MEMORY_SCOPE_AGENT) < tgt)
          __builtin_amdgcn_s_sleep(1);
      }
      __syncthreads();
    }
    asm volatile("" ::: "memory");  // no hoisting h loads above poll
  }
}

// ---------------- host ----------------
extern "C" void kernel_launch(void* const* d_in, const int* in_sizes, int n_in,
                              void* d_out, int out_size, void* d_ws, size_t ws_size,
                              hipStream_t stream) {
  const float* x     = (const float*)d_in[0];
  const float* w_ih0 = (const float*)d_in[1];
  const float* w_hh0 = (const float*)d_in[2];
  const float* b0v   = (const float*)d_in[3];
  const float* w_ihr = (const float*)d_in[4];
  const float* w_hhr = (const float*)d_in[5];
  const float* b_r   = (const float*)d_in[6];
  float* out = (float*)d_out;

  char* ws = (char*)d_ws;
  float*    Xp   = (float*)(ws);                   // 201,326,592 B
  unsigned* hbuf = (unsigned*)(ws + 201326592);    //     262,144 B (packed h words)
  int*      bar  = (int*)(ws + 201588736);         //       8,192 B (~192.3 MiB total)

  float* yBuf     = out;                 // cur region doubles as inter-layer y staging
  float* hOutBase = out + 16777216;
  float* cOutBase = out + 16777216 + 131072;

  hipMemsetAsync(bar, 0, 8192, stream);

  for (int l = 0; l < 4; ++l) {
    const float* wih  = (l == 0) ? w_ih0 : (w_ihr + (size_t)(l - 1) * 3072 * 1024);
    const float* whh  = (l == 0) ? w_hh0 : (w_hhr + (size_t)(l - 1) * 3072 * 1024);
    const float* bias = (l == 0) ? b0v : (b_r + (size_t)(l - 1) * 3072);
    const int K = (l == 0) ? 512 : 1024;
    const float* Ain = (l == 0) ? x : yBuf;
    dim3 ggrid((16384 / BM) * (3072 / BN));
    k_gemm_split<<<ggrid, 256, 0, stream>>>(Ain, wih, bias, Xp, 16384, 3072, K);
    hipMemsetAsync(hbuf, 0, 262144, stream);
    float* hO = hOutBase + (size_t)l * 32768;
    float* cO = cOutBase + (size_t)l * 32768;
    int* barL = bar + l * 512;   // flags[256] + epoch[1] per layer; fresh zeroed region
    void* args[] = { (void*)&Xp, (void*)&whh, (void*)&hbuf, (void*)&yBuf,
                     (void*)&hO, (void*)&cO, (void*)&barL };
    if (hipLaunchCooperativeKernel((void*)k_recurrent, dim3(256), dim3(128),
                                   args, 0, stream) != hipSuccess) {
      // fallback: plain launch (256 blocks, ~55KB LDS, 128 thr -> all co-resident)
      k_recurrent<<<dim3(256), dim3(128), 0, stream>>>(Xp, whh, hbuf, yBuf,
                                                       hO, cO, barL);
    }
  }
}